// Round 11
// baseline (11805.387 us; speedup 1.0000x reference)
//
#include <hip/hip_runtime.h>
#include <hip/hip_bf16.h>

#define D_MODEL 1024
#define N_HEADS 16
#define DH 64
#define CHUNK_LEN 50
#define MEM_LEN 16
#define TT 66            // MEM_LEN + CHUNK_LEN
#define BB 64
#define LL 2000
#define NCHUNK 40
#define MTOK (BB*TT)     // 4224

typedef _Float16 half8_t __attribute__((ext_vector_type(8)));
typedef __attribute__((ext_vector_type(4))) float f32x4;

typedef __attribute__((address_space(1))) const void GVoid;
typedef __attribute__((address_space(3))) void LVoid;

__device__ __forceinline__ void gload16(const void* g, void* l) {
  __builtin_amdgcn_global_load_lds((GVoid*)g, (LVoid*)l, 16, 0, 0);
}

// ---------------- weight fp32 -> fp16 ----------------
__global__ __launch_bounds__(256) void f2h_kernel(const float* __restrict__ in,
                                                  _Float16* __restrict__ out, int n) {
  int i = (blockIdx.x * 256 + threadIdx.x) * 4;
  if (i < n) {
    float4 v = *(const float4*)(in + i);
    out[i+0] = (_Float16)v.x;
    out[i+1] = (_Float16)v.y;
    out[i+2] = (_Float16)v.z;
    out[i+3] = (_Float16)v.w;
  }
}

// ---------------- build z (gather + mem + pos) fused with LN1 ----------------
__global__ __launch_bounds__(256) void build_z_ln(
    const int* __restrict__ in_prob, const int* __restrict__ in_skill,
    const float* __restrict__ emb_p, const float* __restrict__ emb_s,
    const float* __restrict__ mem_src, int mem_bstride,
    const float* __restrict__ pos,
    const float* __restrict__ gam, const float* __restrict__ bet,
    float* __restrict__ z, _Float16* __restrict__ zn, int chunk)
{
  int row = blockIdx.x;                 // 0..MTOK-1
  int b = row / TT, t = row % TT;
  int tid = threadIdx.x;
  int d = tid * 4;
  float4 v;
  if (t < MEM_LEN) {
    v = *(const float4*)(mem_src + (size_t)b*mem_bstride + t*D_MODEL + d);
  } else {
    int tok = chunk*CHUNK_LEN + (t - MEM_LEN);
    int p = in_prob[b*LL + tok];
    int s = in_skill[b*LL + tok];
    float4 vp = *(const float4*)(emb_p + (size_t)p*D_MODEL + d);
    float4 vs = *(const float4*)(emb_s + (size_t)s*D_MODEL + d);
    v = make_float4(vp.x+vs.x, vp.y+vs.y, vp.z+vs.z, vp.w+vs.w);
  }
  float4 pv = *(const float4*)(pos + t*D_MODEL + d);
  v.x += pv.x; v.y += pv.y; v.z += pv.z; v.w += pv.w;
  *(float4*)(z + (size_t)row*D_MODEL + d) = v;
  float sum = v.x+v.y+v.z+v.w;
  float sq  = v.x*v.x+v.y*v.y+v.z*v.z+v.w*v.w;
  #pragma unroll
  for (int off = 32; off; off >>= 1) {
    sum += __shfl_down(sum, off, 64);
    sq  += __shfl_down(sq,  off, 64);
  }
  __shared__ float rs_[4], rq_[4];
  int wave = tid >> 6, lane = tid & 63;
  if (lane == 0) { rs_[wave] = sum; rq_[wave] = sq; }
  __syncthreads();
  sum = rs_[0]+rs_[1]+rs_[2]+rs_[3];
  sq  = rq_[0]+rq_[1]+rq_[2]+rq_[3];
  float mu  = sum * (1.0f/D_MODEL);
  float var = sq  * (1.0f/D_MODEL) - mu*mu;
  float rstd = rsqrtf(var + 1e-5f);
  float4 gv = *(const float4*)(gam + d);
  float4 bv = *(const float4*)(bet + d);
  _Float16* o = zn + (size_t)row*D_MODEL + d;
  o[0] = (_Float16)((v.x-mu)*rstd*gv.x + bv.x);
  o[1] = (_Float16)((v.y-mu)*rstd*gv.y + bv.y);
  o[2] = (_Float16)((v.z-mu)*rstd*gv.z + bv.z);
  o[3] = (_Float16)((v.w-mu)*rstd*gv.w + bv.w);
}

// ---------------- plain LN (z fp32 -> fp16 out) ----------------
__global__ __launch_bounds__(256) void ln_kernel(
    const float* __restrict__ z, const float* __restrict__ gam, const float* __restrict__ bet,
    _Float16* __restrict__ out)
{
  int row = blockIdx.x;
  int tid = threadIdx.x;
  int d = tid * 4;
  float4 v = *(const float4*)(z + (size_t)row*D_MODEL + d);
  float sum = v.x+v.y+v.z+v.w;
  float sq  = v.x*v.x+v.y*v.y+v.z*v.z+v.w*v.w;
  #pragma unroll
  for (int off = 32; off; off >>= 1) {
    sum += __shfl_down(sum, off, 64);
    sq  += __shfl_down(sq,  off, 64);
  }
  __shared__ float rs_[4], rq_[4];
  int wave = tid >> 6, lane = tid & 63;
  if (lane == 0) { rs_[wave] = sum; rq_[wave] = sq; }
  __syncthreads();
  sum = rs_[0]+rs_[1]+rs_[2]+rs_[3];
  sq  = rq_[0]+rq_[1]+rq_[2]+rq_[3];
  float mu  = sum * (1.0f/D_MODEL);
  float var = sq  * (1.0f/D_MODEL) - mu*mu;
  float rstd = rsqrtf(var + 1e-5f);
  float4 gv = *(const float4*)(gam + d);
  float4 bv = *(const float4*)(bet + d);
  _Float16* o = out + (size_t)row*D_MODEL + d;
  o[0] = (_Float16)((v.x-mu)*rstd*gv.x + bv.x);
  o[1] = (_Float16)((v.y-mu)*rstd*gv.y + bv.y);
  o[2] = (_Float16)((v.z-mu)*rstd*gv.z + bv.z);
  o[3] = (_Float16)((v.w-mu)*rstd*gv.w + bv.w);
}

// ---------------- attention (per b,h block), register-tiled ----------------
__global__ __launch_bounds__(256) void attn_kernel(
    const _Float16* __restrict__ qkv, _Float16* __restrict__ attn_o)
{
  __shared__ float qs_t[64*68 + 8];
  __shared__ float ks_t[64*68 + 8];
  __shared__ float vs[TT*DH];
  __shared__ float sc[TT*67];
  int bh = blockIdx.x; int b = bh >> 4, h = bh & 15;
  int tid = threadIdx.x;
  const _Float16* base = qkv + (size_t)b*TT*3072 + h*DH;
  for (int i = tid; i < TT*DH; i += 256) {
    int t = i >> 6, d2 = i & 63;
    const _Float16* rp = base + (size_t)t*3072 + d2;
    qs_t[d2*68 + t] = (float)rp[0];
    ks_t[d2*68 + t] = (float)rp[1024];
    vs[t*64 + d2]   = (float)rp[2048];
  }
  __syncthreads();
  if (tid < 153) {
    int ti = tid / 9, tj = tid % 9;
    int qi0 = ti*4, kj0 = tj*8;
    float acc[4][8];
    #pragma unroll
    for (int i = 0; i < 4; i++)
      #pragma unroll
      for (int j = 0; j < 8; j++) acc[i][j] = 0.f;
    for (int d2 = 0; d2 < 64; d2++) {
      float4 qv = *(const float4*)(qs_t + d2*68 + qi0);
      float4 k0 = *(const float4*)(ks_t + d2*68 + kj0);
      float4 k1 = *(const float4*)(ks_t + d2*68 + kj0 + 4);
      float q_[4] = {qv.x, qv.y, qv.z, qv.w};
      float k_[8] = {k0.x, k0.y, k0.z, k0.w, k1.x, k1.y, k1.z, k1.w};
      #pragma unroll
      for (int i = 0; i < 4; i++)
        #pragma unroll
        for (int j = 0; j < 8; j++)
          acc[i][j] += q_[i]*k_[j];
    }
    #pragma unroll
    for (int i = 0; i < 4; i++) {
      int qi = qi0 + i;
      if (qi >= TT) continue;
      #pragma unroll
      for (int j = 0; j < 8; j++) {
        int kj = kj0 + j;
        if (kj >= TT) continue;
        float s;
        if (qi >= MEM_LEN && kj >= MEM_LEN && kj > qi) s = -1e9f;
        else s = acc[i][j]*0.125f;
        sc[qi*67 + kj] = s;
      }
    }
  }
  __syncthreads();
  if (tid < TT) {
    float* r = sc + tid*67;
    float m = -1e30f;
    for (int j = 0; j < TT; j++) m = fmaxf(m, r[j]);
    float ssum = 0.f;
    for (int j = 0; j < TT; j++) { float e = __expf(r[j]-m); r[j] = e; ssum += e; }
    float inv = 1.f/ssum;
    for (int j = 0; j < TT; j++) r[j] *= inv;
  }
  __syncthreads();
  if (tid < 136) {
    int ti = tid >> 3, tj = tid & 7;
    int qi0 = ti*4, d20 = tj*8;
    float acc[4][8];
    #pragma unroll
    for (int i = 0; i < 4; i++)
      #pragma unroll
      for (int j = 0; j < 8; j++) acc[i][j] = 0.f;
    for (int kj = 0; kj < TT; kj++) {
      float a_[4];
      #pragma unroll
      for (int i = 0; i < 4; i++)
        a_[i] = (qi0 + i < TT) ? sc[(qi0+i)*67 + kj] : 0.f;
      float4 v0 = *(const float4*)(vs + kj*64 + d20);
      float4 v1 = *(const float4*)(vs + kj*64 + d20 + 4);
      float v_[8] = {v0.x, v0.y, v0.z, v0.w, v1.x, v1.y, v1.z, v1.w};
      #pragma unroll
      for (int i = 0; i < 4; i++)
        #pragma unroll
        for (int j = 0; j < 8; j++)
          acc[i][j] += a_[i]*v_[j];
    }
    #pragma unroll
    for (int i = 0; i < 4; i++) {
      int qi = qi0 + i;
      if (qi >= TT) continue;
      _Float16* o = attn_o + ((size_t)b*TT + qi)*D_MODEL + h*DH + d20;
      #pragma unroll
      for (int j = 0; j < 8; j++) o[j] = (_Float16)acc[i][j];
    }
  }
}

// ---------------- finalize+reduce ----------------
__global__ __launch_bounds__(256) void finalize_reduce(
    const float* __restrict__ z, const float* __restrict__ p0, const float* __restrict__ p1,
    const float* __restrict__ b2,
    float* __restrict__ enc_out, float* __restrict__ mem,
    _Float16* __restrict__ mcb, float* __restrict__ mcf, int chunk)
{
  int row = blockIdx.x; int b = row / TT, t = row % TT;
  int d = threadIdx.x * 4;
  size_t idx = (size_t)row*D_MODEL + d;
  float4 v  = *(const float4*)(z  + idx);
  float4 a0 = *(const float4*)(p0 + idx);
  float4 a1 = *(const float4*)(p1 + idx);
  float4 bv = *(const float4*)(b2 + d);
  v.x += a0.x + a1.x + bv.x;
  v.y += a0.y + a1.y + bv.y;
  v.z += a0.z + a1.z + bv.z;
  v.w += a0.w + a1.w + bv.w;
  if (t >= MEM_LEN) {
    size_t o = ((size_t)b*LL + (size_t)chunk*CHUNK_LEN + (t - MEM_LEN))*D_MODEL + d;
    *(float4*)(enc_out + o) = v;
  } else {
    size_t mrow = (size_t)b*MEM_LEN + t;
    if (chunk == 0) {
      *(float4*)(mem + mrow*D_MODEL + d) = v;
    } else {
      *(float4*)(mcf + mrow*D_MODEL + d) = v;
      _Float16* o = mcb + mrow*D_MODEL + d;
      o[0] = (_Float16)v.x;
      o[1] = (_Float16)v.y;
      o[2] = (_Float16)v.z;
      o[3] = (_Float16)v.w;
    }
  }
}

// ---------------- copy mem -> output tail ----------------
__global__ __launch_bounds__(256) void copy_mem_kernel(const float* __restrict__ mem,
                                                       float* __restrict__ out) {
  int i = (blockIdx.x * 256 + threadIdx.x) * 4;
  float4 v = *(const float4*)(mem + i);
  *(float4*)(out + i) = v;
}

// ================= GEMM: 2-buffer counted-vmcnt pipeline + XOR swizzle ==================
// TM=128: 4 waves as 2x2, each 64x64 (acc[4][4]), 4 loads/stage, vmcnt(4).
// TM=64 : 4 waves as 1x4, each 64x32 (acc[4][2]), 3 loads/stage, vmcnt(3).
//         Used for sub-fill dispatches (proj, FFN2): 2x the blocks, half the block time.
// Per-output K-order identical across TM -> bitwise-identical results.
#define EPI_QKV   0
#define EPI_RESID 1
#define EPI_RELU  2
#define EPI_PART  3

#define KSLICE 2048

template<int EPI, int TM = 128>
__global__ __launch_bounds__(256) void gemm_bt(
    const _Float16* __restrict__ A,
    const _Float16* __restrict__ Bw,
    const float* __restrict__ bias,
    float* __restrict__ zres,      // RESID: residual in/out; PART: partial 0
    _Float16* __restrict__ obf,
    float* __restrict__ p1,        // PART: partial 1
    int K, int lda, int ldo)
{
  constexpr int NF = (TM == 128) ? 4 : 2;          // n-frags per wave
  __shared__ short As[2][TM*32];
  __shared__ short Bs[2][128*32];
  int tid = threadIdx.x;
  int lane = tid & 63, wave = tid >> 6;
  int wr = (TM == 128) ? (wave >> 1) : 0;
  int wc = (TM == 128) ? (wave & 1) : wave;
  int tm = blockIdx.y * TM, tn = blockIdx.x * 128;
  f32x4 acc[4][NF] = {};
  const short* Ash = (const short*)A;
  const short* Bsh = (const short*)Bw;
  if constexpr (EPI == EPI_PART) {
    Ash += (size_t)blockIdx.z * KSLICE;
    Bsh += (size_t)blockIdx.z * KSLICE;
  }
  int e0 = tid * 8;
  int r0 = e0 >> 5, c0 = e0 & 31;
  int c0s = c0 ^ (((r0 >> 1) & 3) << 3);   // pre-swizzled global source column
  int ko = (lane >> 4) * 8;
  int rr = lane & 15;
  int kos = ko ^ (((rr >> 1) & 3) << 3);   // read-side XOR

  auto STAGE = [&](int buf, int kt) {
    gload16(Ash + (size_t)(tm + r0)*lda + kt + c0s, (char*)&As[buf][0] + wave*1024);
    if constexpr (TM == 128)
      gload16(Ash + (size_t)(tm + 64 + r0)*lda + kt + c0s, (char*)&As[buf][0] + 4096 + wave*1024);
    gload16(Bsh + (size_t)(tn +      r0)*lda + kt + c0s, (char*)&Bs[buf][0] +        wave*1024);
    gload16(Bsh + (size_t)(tn + 64 + r0)*lda + kt + c0s, (char*)&Bs[buf][0] + 4096 + wave*1024);
  };
  auto COMPUTE = [&](int buf) {
    half8_t af[4], bfr[NF];
    #pragma unroll
    for (int m = 0; m < 4; m++)
      af[m] = *(const half8_t*)(&As[buf][(wr*64 + m*16 + rr)*32 + kos]);
    #pragma unroll
    for (int n = 0; n < NF; n++)
      bfr[n] = *(const half8_t*)(&Bs[buf][(wc*(NF*16) + n*16 + rr)*32 + kos]);
    #pragma unroll
    for (int m = 0; m < 4; m++)
      #pragma unroll
      for (int n = 0; n < NF; n++)
        acc[m][n] = __builtin_amdgcn_mfma_f32_16x16x32_f16(af[m], bfr[n], acc[m][n], 0, 0, 0);
  };

  STAGE(0, 0);
  int cur = 0;
  for (int kt = 32; kt < K; kt += 32) {
    STAGE(cur ^ 1, kt);
    // wait for CURRENT buffer's loads only; next tile's stay in flight
    if constexpr (TM == 128)
      asm volatile("s_waitcnt vmcnt(4)" ::: "memory");
    else
      asm volatile("s_waitcnt vmcnt(3)" ::: "memory");
    __builtin_amdgcn_s_barrier();
    COMPUTE(cur);
    asm volatile("" ::: "memory");
    __builtin_amdgcn_s_barrier();
    cur ^= 1;
  }
  asm volatile("s_waitcnt vmcnt(0)" ::: "memory");
  __builtin_amdgcn_s_barrier();
  COMPUTE(cur);

  int rbase = tm + wr*64 + ((lane >> 4) << 2);
  int cbase = tn + wc*(NF*16) + (lane & 15);
  float* pp = nullptr;
  if constexpr (EPI == EPI_PART) pp = (blockIdx.z == 0) ? zres : p1;
  #pragma unroll
  for (int nn = 0; nn < NF; nn++) {
    int col = cbase + nn*16;
    float bs = (EPI == EPI_PART) ? 0.f : bias[col];
    #pragma unroll
    for (int m = 0; m < 4; m++) {
      #pragma unroll
      for (int i = 0; i < 4; i++) {
        int r = rbase + m*16 + i;
        float v = acc[m][nn][i] + bs;
        if constexpr (EPI == EPI_QKV) {
          obf[(size_t)r*ldo + col] = (_Float16)v;
        } else if constexpr (EPI == EPI_RESID) {
          zres[(size_t)r*D_MODEL + col] += v;
        } else if constexpr (EPI == EPI_RELU) {
          obf[(size_t)r*ldo + col] = (_Float16)fmaxf(v, 0.f);
        } else { // EPI_PART
          pp[(size_t)r*D_MODEL + col] = v;
        }
      }
    }
  }
}

// ---------------- gate GEMM: 64x64 tiles, M=N=K=1024, sigmoid + mem blend ----------------
__global__ __launch_bounds__(256) void gemm_gate64(
    const _Float16* __restrict__ A,
    const _Float16* __restrict__ Bw,
    const float* __restrict__ bias,
    const float* __restrict__ mcf,
    float* __restrict__ mem)
{
  __shared__ short As[64*32];
  __shared__ short Bs[64*32];
  int tid = threadIdx.x;
  int lane = tid & 63, wave = tid >> 6;
  int wr = wave >> 1, wc = wave & 1;
  int tm = blockIdx.y * 64, tn = blockIdx.x * 64;
  f32x4 acc[2][2] = {};
  const short* Ash = (const short*)A;
  const short* Bsh = (const short*)Bw;
  int e0 = tid * 8;
  int r0 = e0 >> 5, c0 = e0 & 31;

  for (int kt = 0; kt < 1024; kt += 32) {
    gload16(Ash + (size_t)(tm + r0)*1024 + kt + c0, (char*)As + wave*1024);
    gload16(Bsh + (size_t)(tn + r0)*1024 + kt + c0, (char*)Bs + wave*1024);
    __syncthreads();
    half8_t af[2], bfr[2];
    int ko = (lane >> 4) * 8;
    int rr = lane & 15;
    #pragma unroll
    for (int m = 0; m < 2; m++)
      af[m] = *(const half8_t*)(As + (wr*32 + m*16 + rr)*32 + ko);
    #pragma unroll
    for (int n = 0; n < 2; n++)
      bfr[n] = *(const half8_t*)(Bs + (wc*32 + n*16 + rr)*32 + ko);
    #pragma unroll
    for (int m = 0; m < 2; m++)
      #pragma unroll
      for (int n = 0; n < 2; n++)
        acc[m][n] = __builtin_amdgcn_mfma_f32_16x16x32_f16(af[m], bfr[n], acc[m][n], 0, 0, 0);
    __syncthreads();
  }

  int rbase = tm + wr*32 + ((lane >> 4) << 2);
  int cbase = tn + wc*32 + (lane & 15);
  #pragma unroll
  for (int n = 0; n < 2; n++) {
    int col = cbase + n*16;
    float bs = bias[col];
    #pragma unroll
    for (int m = 0; m < 2; m++) {
      #pragma unroll
      for (int i = 0; i < 4; i++) {
        int r = rbase + m*16 + i;
        float g = 1.f / (1.f + __expf(-(acc[m][n][i] + bs)));
        size_t mi = (size_t)r*D_MODEL + col;
        mem[mi] = g*mcf[mi] + (1.f - g)*mem[mi];
      }
    }
  }
}

extern "C" void kernel_launch(void* const* d_in, const int* in_sizes, int n_in,
                              void* d_out, int out_size, void* d_ws, size_t ws_size,
                              hipStream_t stream) {
  const int*   in_prob  = (const int*)d_in[0];
  const int*   in_skill = (const int*)d_in[1];
  const float* emb_p    = (const float*)d_in[2];
  const float* emb_s    = (const float*)d_in[3];
  const float* mem_init = (const float*)d_in[4];
  const float* pos      = (const float*)d_in[5];
  const float* w_qkv    = (const float*)d_in[6];
  const float* b_qkv    = (const float*)d_in[7];
  const float* w_out    = (const float*)d_in[8];
  const float* b_out    = (const float*)d_in[9];
  const float* w1       = (const float*)d_in[10];
  const float* b1       = (const float*)d_in[11];
  const float* w2       = (const float*)d_in[12];
  const float* b2       = (const float*)d_in[13];
  const float* g_attn   = (const float*)d_in[14];
  const float* be_attn  = (const float*)d_in[15];
  const float* g_ffn    = (const float*)d_in[16];
  const float* be_ffn   = (const float*)d_in[17];
  const float* w_gate   = (const float*)d_in[18];
  const float* b_gate   = (const float*)d_in[19];

  float* enc_out = (float*)d_out;
  float* mem_out = enc_out + (size_t)BB*LL*D_MODEL;

  char* ws = (char*)d_ws;
  size_t off = 0;
  auto alloc = [&](size_t bytes) -> char* {
    char* p = ws + off;
    off += (bytes + 255) & ~(size_t)255;
    return p;
  };
  _Float16* wqkv_h = (_Float16*)alloc((size_t)3072*1024*2);
  _Float16* wout_h = (_Float16*)alloc((size_t)1024*1024*2);
  _Float16* w1_h   = (_Float16*)alloc((size_t)4096*1024*2);
  _Float16* w2_h   = (_Float16*)alloc((size_t)1024*4096*2);
  _Float16* wgate_h= (_Float16*)alloc((size_t)1024*1024*2);
  float*    z      = (float*)alloc((size_t)MTOK*D_MODEL*4);
  _Float16* zn     = (_Float16*)alloc((size_t)MTOK*D_MODEL*2);
  _Float16* qkv    = (_Float16*)alloc((size_t)MTOK*3072*2);
  _Float16* ao     = (_Float16*)alloc((size_t)MTOK*D_MODEL*2);
  _Float16* hb     = (_Float16*)alloc((size_t)MTOK*D_MODEL*2);
  _Float16* fh     = (_Float16*)alloc((size_t)MTOK*4096*2);
  _Float16* mcb    = (_Float16*)alloc((size_t)1024*1024*2);
  float*    mem    = (float*)alloc((size_t)1024*1024*4);
  float*    mcf    = (float*)alloc((size_t)1024*1024*4);
  float*    part0  = (float*)alloc((size_t)MTOK*D_MODEL*4);
  float*    part1  = (float*)alloc((size_t)MTOK*D_MODEL*4);
  if (off > ws_size) return;

  // weights -> fp16 (once per call)
  f2h_kernel<<<(3072*1024)/1024, 256, 0, stream>>>(w_qkv, wqkv_h, 3072*1024);
  f2h_kernel<<<(1024*1024)/1024, 256, 0, stream>>>(w_out, wout_h, 1024*1024);
  f2h_kernel<<<(4096*1024)/1024, 256, 0, stream>>>(w1, w1_h, 4096*1024);
  f2h_kernel<<<(1024*4096)/1024, 256, 0, stream>>>(w2, w2_h, 1024*4096);
  f2h_kernel<<<(1024*1024)/1024, 256, 0, stream>>>(w_gate, wgate_h, 1024*1024);

  for (int c = 0; c < NCHUNK; c++) {
    const float* msrc = (c == 0) ? mem_init : mem;
    int mbs = (c == 0) ? 0 : MEM_LEN*D_MODEL;
    build_z_ln<<<MTOK, 256, 0, stream>>>(in_prob, in_skill, emb_p, emb_s,
                                         msrc, mbs, pos, g_attn, be_attn, z, zn, c);
    gemm_bt<EPI_QKV><<<dim3(3072/128, MTOK/128), 256, 0, stream>>>(
        zn, wqkv_h, b_qkv, nullptr, qkv, nullptr, 1024, 1024, 3072);
    attn_kernel<<<BB*N_HEADS, 256, 0, stream>>>(qkv, ao);
    // proj: sub-fill dispatch -> TM=64 (528 blocks, half block time)
    gemm_bt<EPI_RESID, 64><<<dim3(1024/128, MTOK/64), 256, 0, stream>>>(
        ao, wout_h, b_out, z, nullptr, nullptr, 1024, 1024, 1024);
    ln_kernel<<<MTOK, 256, 0, stream>>>(z, g_ffn, be_ffn, hb);
    gemm_bt<EPI_RELU><<<dim3(4096/128, MTOK/128), 256, 0, stream>>>(
        hb, w1_h, b1, nullptr, fh, nullptr, 1024, 1024, 4096);
    // FFN2 split-K: sub-fill dispatch -> TM=64 (1056 blocks)
    gemm_bt<EPI_PART, 64><<<dim3(1024/128, MTOK/64, 2), 256, 0, stream>>>(
        fh, w2_h, nullptr, part0, nullptr, part1, KSLICE, 4096, 1024);
    finalize_reduce<<<MTOK, 256, 0, stream>>>(z, part0, part1, b2,
                                              enc_out, mem, mcb, mcf, c);
    if (c > 0) {
      gemm_gate64<<<dim3(1024/64, 1024/64), 256, 0, stream>>>(
          mcb, wgate_h, b_gate, mcf, mem);
    }
  }
  copy_mem_kernel<<<(1024*1024)/1024, 256, 0, stream>>>(mem, mem_out);
}

// Round 12
// 10854.832 us; speedup vs baseline: 1.0876x; 1.0876x over previous
//
#include <hip/hip_runtime.h>
#include <hip/hip_bf16.h>

#define D_MODEL 1024
#define N_HEADS 16
#define DH 64
#define CHUNK_LEN 50
#define MEM_LEN 16
#define TT 66            // MEM_LEN + CHUNK_LEN
#define BB 64
#define LL 2000
#define NCHUNK 40
#define MTOK (BB*TT)     // 4224
#define MTOKP 4352       // padded to 17*256 for the 256-tile QKV

typedef _Float16 half8_t __attribute__((ext_vector_type(8)));
typedef __attribute__((ext_vector_type(4))) float f32x4;

typedef __attribute__((address_space(1))) const void GVoid;
typedef __attribute__((address_space(3))) void LVoid;

__device__ __forceinline__ void gload16(const void* g, void* l) {
  __builtin_amdgcn_global_load_lds((GVoid*)g, (LVoid*)l, 16, 0, 0);
}

// ---------------- weight fp32 -> fp16 ----------------
__global__ __launch_bounds__(256) void f2h_kernel(const float* __restrict__ in,
                                                  _Float16* __restrict__ out, int n) {
  int i = (blockIdx.x * 256 + threadIdx.x) * 4;
  if (i < n) {
    float4 v = *(const float4*)(in + i);
    out[i+0] = (_Float16)v.x;
    out[i+1] = (_Float16)v.y;
    out[i+2] = (_Float16)v.z;
    out[i+3] = (_Float16)v.w;
  }
}

// ---------------- build z (gather + mem + pos) fused with LN1 ----------------
__global__ __launch_bounds__(256) void build_z_ln(
    const int* __restrict__ in_prob, const int* __restrict__ in_skill,
    const float* __restrict__ emb_p, const float* __restrict__ emb_s,
    const float* __restrict__ mem_src, int mem_bstride,
    const float* __restrict__ pos,
    const float* __restrict__ gam, const float* __restrict__ bet,
    float* __restrict__ z, _Float16* __restrict__ zn, int chunk)
{
  int row = blockIdx.x;                 // 0..MTOK-1
  int b = row / TT, t = row % TT;
  int tid = threadIdx.x;
  int d = tid * 4;
  float4 v;
  if (t < MEM_LEN) {
    v = *(const float4*)(mem_src + (size_t)b*mem_bstride + t*D_MODEL + d);
  } else {
    int tok = chunk*CHUNK_LEN + (t - MEM_LEN);
    int p = in_prob[b*LL + tok];
    int s = in_skill[b*LL + tok];
    float4 vp = *(const float4*)(emb_p + (size_t)p*D_MODEL + d);
    float4 vs = *(const float4*)(emb_s + (size_t)s*D_MODEL + d);
    v = make_float4(vp.x+vs.x, vp.y+vs.y, vp.z+vs.z, vp.w+vs.w);
  }
  float4 pv = *(const float4*)(pos + t*D_MODEL + d);
  v.x += pv.x; v.y += pv.y; v.z += pv.z; v.w += pv.w;
  *(float4*)(z + (size_t)row*D_MODEL + d) = v;
  float sum = v.x+v.y+v.z+v.w;
  float sq  = v.x*v.x+v.y*v.y+v.z*v.z+v.w*v.w;
  #pragma unroll
  for (int off = 32; off; off >>= 1) {
    sum += __shfl_down(sum, off, 64);
    sq  += __shfl_down(sq,  off, 64);
  }
  __shared__ float rs_[4], rq_[4];
  int wave = tid >> 6, lane = tid & 63;
  if (lane == 0) { rs_[wave] = sum; rq_[wave] = sq; }
  __syncthreads();
  sum = rs_[0]+rs_[1]+rs_[2]+rs_[3];
  sq  = rq_[0]+rq_[1]+rq_[2]+rq_[3];
  float mu  = sum * (1.0f/D_MODEL);
  float var = sq  * (1.0f/D_MODEL) - mu*mu;
  float rstd = rsqrtf(var + 1e-5f);
  float4 gv = *(const float4*)(gam + d);
  float4 bv = *(const float4*)(bet + d);
  _Float16* o = zn + (size_t)row*D_MODEL + d;
  o[0] = (_Float16)((v.x-mu)*rstd*gv.x + bv.x);
  o[1] = (_Float16)((v.y-mu)*rstd*gv.y + bv.y);
  o[2] = (_Float16)((v.z-mu)*rstd*gv.z + bv.z);
  o[3] = (_Float16)((v.w-mu)*rstd*gv.w + bv.w);
}

// ---------------- plain LN (z fp32 -> fp16 out) ----------------
__global__ __launch_bounds__(256) void ln_kernel(
    const float* __restrict__ z, const float* __restrict__ gam, const float* __restrict__ bet,
    _Float16* __restrict__ out)
{
  int row = blockIdx.x;
  int tid = threadIdx.x;
  int d = tid * 4;
  float4 v = *(const float4*)(z + (size_t)row*D_MODEL + d);
  float sum = v.x+v.y+v.z+v.w;
  float sq  = v.x*v.x+v.y*v.y+v.z*v.z+v.w*v.w;
  #pragma unroll
  for (int off = 32; off; off >>= 1) {
    sum += __shfl_down(sum, off, 64);
    sq  += __shfl_down(sq,  off, 64);
  }
  __shared__ float rs_[4], rq_[4];
  int wave = tid >> 6, lane = tid & 63;
  if (lane == 0) { rs_[wave] = sum; rq_[wave] = sq; }
  __syncthreads();
  sum = rs_[0]+rs_[1]+rs_[2]+rs_[3];
  sq  = rq_[0]+rq_[1]+rq_[2]+rq_[3];
  float mu  = sum * (1.0f/D_MODEL);
  float var = sq  * (1.0f/D_MODEL) - mu*mu;
  float rstd = rsqrtf(var + 1e-5f);
  float4 gv = *(const float4*)(gam + d);
  float4 bv = *(const float4*)(bet + d);
  _Float16* o = out + (size_t)row*D_MODEL + d;
  o[0] = (_Float16)((v.x-mu)*rstd*gv.x + bv.x);
  o[1] = (_Float16)((v.y-mu)*rstd*gv.y + bv.y);
  o[2] = (_Float16)((v.z-mu)*rstd*gv.z + bv.z);
  o[3] = (_Float16)((v.w-mu)*rstd*gv.w + bv.w);
}

// ---------------- attention (per b,h block), register-tiled ----------------
__global__ __launch_bounds__(256) void attn_kernel(
    const _Float16* __restrict__ qkv, _Float16* __restrict__ attn_o)
{
  __shared__ float qs_t[64*68 + 8];
  __shared__ float ks_t[64*68 + 8];
  __shared__ float vs[TT*DH];
  __shared__ float sc[TT*67];
  int bh = blockIdx.x; int b = bh >> 4, h = bh & 15;
  int tid = threadIdx.x;
  const _Float16* base = qkv + (size_t)b*TT*3072 + h*DH;
  for (int i = tid; i < TT*DH; i += 256) {
    int t = i >> 6, d2 = i & 63;
    const _Float16* rp = base + (size_t)t*3072 + d2;
    qs_t[d2*68 + t] = (float)rp[0];
    ks_t[d2*68 + t] = (float)rp[1024];
    vs[t*64 + d2]   = (float)rp[2048];
  }
  __syncthreads();
  if (tid < 153) {
    int ti = tid / 9, tj = tid % 9;
    int qi0 = ti*4, kj0 = tj*8;
    float acc[4][8];
    #pragma unroll
    for (int i = 0; i < 4; i++)
      #pragma unroll
      for (int j = 0; j < 8; j++) acc[i][j] = 0.f;
    for (int d2 = 0; d2 < 64; d2++) {
      float4 qv = *(const float4*)(qs_t + d2*68 + qi0);
      float4 k0 = *(const float4*)(ks_t + d2*68 + kj0);
      float4 k1 = *(const float4*)(ks_t + d2*68 + kj0 + 4);
      float q_[4] = {qv.x, qv.y, qv.z, qv.w};
      float k_[8] = {k0.x, k0.y, k0.z, k0.w, k1.x, k1.y, k1.z, k1.w};
      #pragma unroll
      for (int i = 0; i < 4; i++)
        #pragma unroll
        for (int j = 0; j < 8; j++)
          acc[i][j] += q_[i]*k_[j];
    }
    #pragma unroll
    for (int i = 0; i < 4; i++) {
      int qi = qi0 + i;
      if (qi >= TT) continue;
      #pragma unroll
      for (int j = 0; j < 8; j++) {
        int kj = kj0 + j;
        if (kj >= TT) continue;
        float s;
        if (qi >= MEM_LEN && kj >= MEM_LEN && kj > qi) s = -1e9f;
        else s = acc[i][j]*0.125f;
        sc[qi*67 + kj] = s;
      }
    }
  }
  __syncthreads();
  if (tid < TT) {
    float* r = sc + tid*67;
    float m = -1e30f;
    for (int j = 0; j < TT; j++) m = fmaxf(m, r[j]);
    float ssum = 0.f;
    for (int j = 0; j < TT; j++) { float e = __expf(r[j]-m); r[j] = e; ssum += e; }
    float inv = 1.f/ssum;
    for (int j = 0; j < TT; j++) r[j] *= inv;
  }
  __syncthreads();
  if (tid < 136) {
    int ti = tid >> 3, tj = tid & 7;
    int qi0 = ti*4, d20 = tj*8;
    float acc[4][8];
    #pragma unroll
    for (int i = 0; i < 4; i++)
      #pragma unroll
      for (int j = 0; j < 8; j++) acc[i][j] = 0.f;
    for (int kj = 0; kj < TT; kj++) {
      float a_[4];
      #pragma unroll
      for (int i = 0; i < 4; i++)
        a_[i] = (qi0 + i < TT) ? sc[(qi0+i)*67 + kj] : 0.f;
      float4 v0 = *(const float4*)(vs + kj*64 + d20);
      float4 v1 = *(const float4*)(vs + kj*64 + d20 + 4);
      float v_[8] = {v0.x, v0.y, v0.z, v0.w, v1.x, v1.y, v1.z, v1.w};
      #pragma unroll
      for (int i = 0; i < 4; i++)
        #pragma unroll
        for (int j = 0; j < 8; j++)
          acc[i][j] += a_[i]*v_[j];
    }
    #pragma unroll
    for (int i = 0; i < 4; i++) {
      int qi = qi0 + i;
      if (qi >= TT) continue;
      _Float16* o = attn_o + ((size_t)b*TT + qi)*D_MODEL + h*DH + d20;
      #pragma unroll
      for (int j = 0; j < 8; j++) o[j] = (_Float16)acc[i][j];
    }
  }
}

// ---------------- finalize+reduce ----------------
__global__ __launch_bounds__(256) void finalize_reduce(
    const float* __restrict__ z, const float* __restrict__ p0, const float* __restrict__ p1,
    const float* __restrict__ b2,
    float* __restrict__ enc_out, float* __restrict__ mem,
    _Float16* __restrict__ mcb, float* __restrict__ mcf, int chunk)
{
  int row = blockIdx.x; int b = row / TT, t = row % TT;
  int d = threadIdx.x * 4;
  size_t idx = (size_t)row*D_MODEL + d;
  float4 v  = *(const float4*)(z  + idx);
  float4 a0 = *(const float4*)(p0 + idx);
  float4 a1 = *(const float4*)(p1 + idx);
  float4 bv = *(const float4*)(b2 + d);
  v.x += a0.x + a1.x + bv.x;
  v.y += a0.y + a1.y + bv.y;
  v.z += a0.z + a1.z + bv.z;
  v.w += a0.w + a1.w + bv.w;
  if (t >= MEM_LEN) {
    size_t o = ((size_t)b*LL + (size_t)chunk*CHUNK_LEN + (t - MEM_LEN))*D_MODEL + d;
    *(float4*)(enc_out + o) = v;
  } else {
    size_t mrow = (size_t)b*MEM_LEN + t;
    if (chunk == 0) {
      *(float4*)(mem + mrow*D_MODEL + d) = v;
    } else {
      *(float4*)(mcf + mrow*D_MODEL + d) = v;
      _Float16* o = mcb + mrow*D_MODEL + d;
      o[0] = (_Float16)v.x;
      o[1] = (_Float16)v.y;
      o[2] = (_Float16)v.z;
      o[3] = (_Float16)v.w;
    }
  }
}

// ================= QKV GEMM: 256x256 tile, 8 waves, 8-phase-style schedule =================
// 512 thr; per-wave 128x64 out; BK=64 double-buffered (128KB LDS); counted vmcnt(8)
// (tile i+1 stays in flight across barriers); 4 MFMA-cluster phases/K-step with setprio;
// (row&7)<<3 XOR swizzle both-sides. Per-output K-chunk order identical to the 128-tile
// kernel -> bitwise-identical output.
__global__ __launch_bounds__(512) void gemm_qkv256(
    const _Float16* __restrict__ A,    // zn padded [MTOKP][1024]
    const _Float16* __restrict__ Bw,   // wqkv [3072][1024]
    const float* __restrict__ bias,
    _Float16* __restrict__ obf,        // qkv padded [MTOKP][3072]
    int K, int lda, int ldo)
{
  __shared__ short As[2][256*64];
  __shared__ short Bs[2][256*64];
  int tid = threadIdx.x;
  int lane = tid & 63, wave = tid >> 6;
  int wr = wave >> 2, wcn = wave & 3;       // 2 M-waves x 4 N-waves
  int tm = blockIdx.y * 256, tn = blockIdx.x * 256;
  f32x4 acc[8][4] = {};
  const short* Ash = (const short*)A;
  const short* Bsh = (const short*)Bw;
  int r0 = tid >> 3;                        // 0..63 (row within 64-row slot)
  int c0 = (tid & 7) * 8;                   // 0..56 shorts
  int c0s = c0 ^ ((r0 & 7) << 3);           // pre-swizzled global source col
  int rr = lane & 15;
  int ko = (lane >> 4) * 8;
  int swz = (rr & 7) << 3;                  // read-side XOR (shorts)

  auto STAGE = [&](int buf, int kt) {
    #pragma unroll
    for (int s = 0; s < 4; s++) {
      gload16(Ash + (size_t)(tm + s*64 + r0)*lda + kt + c0s,
              (char*)(&As[buf][0] + s*4096) + wave*1024);
      gload16(Bsh + (size_t)(tn + s*64 + r0)*lda + kt + c0s,
              (char*)(&Bs[buf][0] + s*4096) + wave*1024);
    }
  };
  auto PHASE = [&](int buf, int mh, int ks) {
    half8_t af[4], bf[4];
    #pragma unroll
    for (int m = 0; m < 4; m++) {
      int row = wr*128 + (mh*4 + m)*16 + rr;
      af[m] = *(const half8_t*)(&As[buf][row*64 + ((ks*32 + ko) ^ swz)]);
    }
    #pragma unroll
    for (int n = 0; n < 4; n++) {
      int row = wcn*64 + n*16 + rr;
      bf[n] = *(const half8_t*)(&Bs[buf][row*64 + ((ks*32 + ko) ^ swz)]);
    }
    __builtin_amdgcn_s_setprio(1);
    #pragma unroll
    for (int m = 0; m < 4; m++)
      #pragma unroll
      for (int n = 0; n < 4; n++)
        acc[mh*4+m][n] = __builtin_amdgcn_mfma_f32_16x16x32_f16(af[m], bf[n], acc[mh*4+m][n], 0, 0, 0);
    __builtin_amdgcn_s_setprio(0);
  };

  STAGE(0, 0);
  STAGE(1, 64);
  int nks = K >> 6;                         // 16 K-steps of 64
  for (int i = 0; i < nks; i++) {
    int cb = i & 1;
    if (i < nks - 1)
      asm volatile("s_waitcnt vmcnt(8)" ::: "memory");   // tile i landed; i+1 in flight
    else
      asm volatile("s_waitcnt vmcnt(0)" ::: "memory");
    __builtin_amdgcn_s_barrier();
    // K ascending per output: ks=0 (both M-halves) then ks=1
    PHASE(cb, 0, 0); PHASE(cb, 1, 0); PHASE(cb, 0, 1); PHASE(cb, 1, 1);
    asm volatile("" ::: "memory");
    __builtin_amdgcn_s_barrier();                         // all reads of cb consumed
    if (i < nks - 2) STAGE(cb, (i + 2) << 6);             // overwrite freed buffer
  }

  int rbase = tm + wr*128 + ((lane >> 4) << 2);
  int cbase = tn + wcn*64 + (lane & 15);
  #pragma unroll
  for (int nf = 0; nf < 4; nf++) {
    int col = cbase + nf*16;
    float bs = bias[col];
    #pragma unroll
    for (int mf = 0; mf < 8; mf++) {
      #pragma unroll
      for (int i = 0; i < 4; i++) {
        int r = rbase + mf*16 + i;
        obf[(size_t)r*ldo + col] = (_Float16)(acc[mf][nf][i] + bs);
      }
    }
  }
}

// ================= GEMM 128x128 (R5 exact: 2-buffer counted vmcnt(4) + XOR swizzle) ==========
#define EPI_QKV   0
#define EPI_RESID 1
#define EPI_RELU  2
#define EPI_PART  3

#define KSLICE 2048

template<int EPI>
__global__ __launch_bounds__(256) void gemm_bt(
    const _Float16* __restrict__ A,
    const _Float16* __restrict__ Bw,
    const float* __restrict__ bias,
    float* __restrict__ zres,      // RESID: residual in/out; PART: partial 0
    _Float16* __restrict__ obf,
    float* __restrict__ p1,        // PART: partial 1
    int K, int lda, int ldo)
{
  __shared__ short As[2][128*32];
  __shared__ short Bs[2][128*32];
  int tid = threadIdx.x;
  int lane = tid & 63, wave = tid >> 6;
  int wr = wave >> 1, wc = wave & 1;
  int tm = blockIdx.y * 128, tn = blockIdx.x * 128;
  f32x4 acc[4][4] = {};
  const short* Ash = (const short*)A;
  const short* Bsh = (const short*)Bw;
  if constexpr (EPI == EPI_PART) {
    Ash += (size_t)blockIdx.z * KSLICE;
    Bsh += (size_t)blockIdx.z * KSLICE;
  }
  int e0 = tid * 8;
  int r0 = e0 >> 5, c0 = e0 & 31;
  int c0s = c0 ^ (((r0 >> 1) & 3) << 3);
  int ko = (lane >> 4) * 8;
  int rr = lane & 15;
  int kos = ko ^ (((rr >> 1) & 3) << 3);

  auto STAGE = [&](int buf, int kt) {
    gload16(Ash + (size_t)(tm +      r0)*lda + kt + c0s, (char*)&As[buf][0] +        wave*1024);
    gload16(Ash + (size_t)(tm + 64 + r0)*lda + kt + c0s, (char*)&As[buf][0] + 4096 + wave*1024);
    gload16(Bsh + (size_t)(tn +      r0)*lda + kt + c0s, (char*)&Bs[buf][0] +        wave*1024);
    gload16(Bsh + (size_t)(tn + 64 + r0)*lda + kt + c0s, (char*)&Bs[buf][0] + 4096 + wave*1024);
  };
  auto COMPUTE = [&](int buf) {
    half8_t af[4], bfr[4];
    #pragma unroll
    for (int m = 0; m < 4; m++)
      af[m] = *(const half8_t*)(&As[buf][(wr*64 + m*16 + rr)*32 + kos]);
    #pragma unroll
    for (int n = 0; n < 4; n++)
      bfr[n] = *(const half8_t*)(&Bs[buf][(wc*64 + n*16 + rr)*32 + kos]);
    #pragma unroll
    for (int m = 0; m < 4; m++)
      #pragma unroll
      for (int n = 0; n < 4; n++)
        acc[m][n] = __builtin_amdgcn_mfma_f32_16x16x32_f16(af[m], bfr[n], acc[m][n], 0, 0, 0);
  };

  STAGE(0, 0);
  int cur = 0;
  for (int kt = 32; kt < K; kt += 32) {
    STAGE(cur ^ 1, kt);
    asm volatile("s_waitcnt vmcnt(4)" ::: "memory");
    __builtin_amdgcn_s_barrier();
    COMPUTE(cur);
    asm volatile("" ::: "memory");
    __builtin_amdgcn_s_barrier();
    cur ^= 1;
  }
  asm volatile("s_waitcnt vmcnt(0)" ::: "memory");
  __builtin_amdgcn_s_barrier();
  COMPUTE(cur);

  int rbase = tm + wr*64 + ((lane >> 4) << 2);
  int cbase = tn + wc*64 + (lane & 15);
  float* pp = nullptr;
  if constexpr (EPI == EPI_PART) pp = (blockIdx.z == 0) ? zres : p1;
  #pragma unroll
  for (int nn = 0; nn < 4; nn++) {
    int col = cbase + nn*16;
    float bs = (EPI == EPI_PART) ? 0.f : bias[col];
    #pragma unroll
    for (int m = 0; m < 4; m++) {
      #pragma unroll
      for (int i = 0; i < 4; i++) {
        int r = rbase + m*16 + i;
        float v = acc[m][nn][i] + bs;
        if constexpr (EPI == EPI_QKV) {
          obf[(size_t)r*ldo + col] = (_Float16)v;
        } else if constexpr (EPI == EPI_RESID) {
          zres[(size_t)r*D_MODEL + col] += v;
        } else if constexpr (EPI == EPI_RELU) {
          obf[(size_t)r*ldo + col] = (_Float16)fmaxf(v, 0.f);
        } else { // EPI_PART
          pp[(size_t)r*D_MODEL + col] = v;
        }
      }
    }
  }
}

// ---------------- gate GEMM (R5 exact) ----------------
__global__ __launch_bounds__(256) void gemm_gate64(
    const _Float16* __restrict__ A,
    const _Float16* __restrict__ Bw,
    const float* __restrict__ bias,
    const float* __restrict__ mcf,
    float* __restrict__ mem)
{
  __shared__ short As[64*32];
  __shared__ short Bs[64*32];
  int tid = threadIdx.x;
  int lane = tid & 63, wave = tid >> 6;
  int wr = wave >> 1, wc = wave & 1;
  int tm = blockIdx.y * 64, tn = blockIdx.x * 64;
  f32x4 acc[2][2] = {};
  const short* Ash = (const short*)A;
  const short* Bsh = (const short*)Bw;
  int e0 = tid * 8;
  int r0 = e0 >> 5, c0 = e0 & 31;

  for (int kt = 0; kt < 1024; kt += 32) {
    gload16(Ash + (size_t)(tm + r0)*1024 + kt + c0, (char*)As + wave*1024);
    gload16(Bsh + (size_t)(tn + r0)*1024 + kt + c0, (char*)Bs + wave*1024);
    __syncthreads();
    half8_t af[2], bfr[2];
    int ko = (lane >> 4) * 8;
    int rr = lane & 15;
    #pragma unroll
    for (int m = 0; m < 2; m++)
      af[m] = *(const half8_t*)(As + (wr*32 + m*16 + rr)*32 + ko);
    #pragma unroll
    for (int n = 0; n < 2; n++)
      bfr[n] = *(const half8_t*)(Bs + (wc*32 + n*16 + rr)*32 + ko);
    #pragma unroll
    for (int m = 0; m < 2; m++)
      #pragma unroll
      for (int n = 0; n < 2; n++)
        acc[m][n] = __builtin_amdgcn_mfma_f32_16x16x32_f16(af[m], bfr[n], acc[m][n], 0, 0, 0);
    __syncthreads();
  }

  int rbase = tm + wr*32 + ((lane >> 4) << 2);
  int cbase = tn + wc*32 + (lane & 15);
  #pragma unroll
  for (int n = 0; n < 2; n++) {
    int col = cbase + n*16;
    float bs = bias[col];
    #pragma unroll
    for (int m = 0; m < 2; m++) {
      #pragma unroll
      for (int i = 0; i < 4; i++) {
        int r = rbase + m*16 + i;
        float g = 1.f / (1.f + __expf(-(acc[m][n][i] + bs)));
        size_t mi = (size_t)r*D_MODEL + col;
        mem[mi] = g*mcf[mi] + (1.f - g)*mem[mi];
      }
    }
  }
}

extern "C" void kernel_launch(void* const* d_in, const int* in_sizes, int n_in,
                              void* d_out, int out_size, void* d_ws, size_t ws_size,
                              hipStream_t stream) {
  const int*   in_prob  = (const int*)d_in[0];
  const int*   in_skill = (const int*)d_in[1];
  const float* emb_p    = (const float*)d_in[2];
  const float* emb_s    = (const float*)d_in[3];
  const float* mem_init = (const float*)d_in[4];
  const float* pos      = (const float*)d_in[5];
  const float* w_qkv    = (const float*)d_in[6];
  const float* b_qkv    = (const float*)d_in[7];
  const float* w_out    = (const float*)d_in[8];
  const float* b_out    = (const float*)d_in[9];
  const float* w1       = (const float*)d_in[10];
  const float* b1       = (const float*)d_in[11];
  const float* w2       = (const float*)d_in[12];
  const float* b2       = (const float*)d_in[13];
  const float* g_attn   = (const float*)d_in[14];
  const float* be_attn  = (const float*)d_in[15];
  const float* g_ffn    = (const float*)d_in[16];
  const float* be_ffn   = (const float*)d_in[17];
  const float* w_gate   = (const float*)d_in[18];
  const float* b_gate   = (const float*)d_in[19];

  float* enc_out = (float*)d_out;
  float* mem     = enc_out + (size_t)BB*LL*D_MODEL;   // mem lives directly in d_out tail

  char* ws = (char*)d_ws;
  size_t off = 0;
  auto alloc = [&](size_t bytes) -> char* {
    char* p = ws + off;
    off += (bytes + 255) & ~(size_t)255;
    return p;
  };
  _Float16* wqkv_h = (_Float16*)alloc((size_t)3072*1024*2);
  _Float16* wout_h = (_Float16*)alloc((size_t)1024*1024*2);
  _Float16* w1_h   = (_Float16*)alloc((size_t)4096*1024*2);
  _Float16* w2_h   = (_Float16*)alloc((size_t)1024*4096*2);
  _Float16* wgate_h= (_Float16*)alloc((size_t)1024*1024*2);
  float*    z      = (float*)alloc((size_t)MTOK*D_MODEL*4);
  _Float16* zn     = (_Float16*)alloc((size_t)MTOKP*D_MODEL*2);   // padded rows
  _Float16* qkv    = (_Float16*)alloc((size_t)MTOKP*3072*2);      // padded rows
  _Float16* ao     = (_Float16*)alloc((size_t)MTOK*D_MODEL*2);
  _Float16* hb     = (_Float16*)alloc((size_t)MTOK*D_MODEL*2);
  _Float16* fh     = (_Float16*)alloc((size_t)MTOK*4096*2);
  _Float16* mcb    = (_Float16*)alloc((size_t)1024*1024*2);
  float*    mcf    = (float*)alloc((size_t)1024*1024*4);
  float*    part0  = (float*)alloc((size_t)MTOK*D_MODEL*4);
  float*    part1  = (float*)alloc((size_t)MTOK*D_MODEL*4);
  if (off > ws_size) return;

  // weights -> fp16 (once per call)
  f2h_kernel<<<(3072*1024)/1024, 256, 0, stream>>>(w_qkv, wqkv_h, 3072*1024);
  f2h_kernel<<<(1024*1024)/1024, 256, 0, stream>>>(w_out, wout_h, 1024*1024);
  f2h_kernel<<<(4096*1024)/1024, 256, 0, stream>>>(w1, w1_h, 4096*1024);
  f2h_kernel<<<(1024*4096)/1024, 256, 0, stream>>>(w2, w2_h, 1024*4096);
  f2h_kernel<<<(1024*1024)/1024, 256, 0, stream>>>(w_gate, wgate_h, 1024*1024);

  for (int c = 0; c < NCHUNK; c++) {
    const float* msrc = (c == 0) ? mem_init : mem;
    int mbs = (c == 0) ? 0 : MEM_LEN*D_MODEL;
    build_z_ln<<<MTOK, 256, 0, stream>>>(in_prob, in_skill, emb_p, emb_s,
                                         msrc, mbs, pos, g_attn, be_attn, z, zn, c);
    // QKV: 256-tile 8-phase-style kernel (M padded to 4352; padded rows unused)
    gemm_qkv256<<<dim3(3072/256, MTOKP/256), 512, 0, stream>>>(
        zn, wqkv_h, b_qkv, qkv, 1024, 1024, 3072);
    attn_kernel<<<BB*N_HEADS, 256, 0, stream>>>(qkv, ao);
    gemm_bt<EPI_RESID><<<dim3(1024/128, MTOK/128), 256, 0, stream>>>(
        ao, wout_h, b_out, z, nullptr, nullptr, 1024, 1024, 1024);
    ln_kernel<<<MTOK, 256, 0, stream>>>(z, g_ffn, be_ffn, hb);
    gemm_bt<EPI_RELU><<<dim3(4096/128, MTOK/128), 256, 0, stream>>>(
        hb, w1_h, b1, nullptr, fh, nullptr, 1024, 1024, 4096);
    gemm_bt<EPI_PART><<<dim3(1024/128, MTOK/128, 2), 256, 0, stream>>>(
        fh, w2_h, nullptr, part0, nullptr, part1, KSLICE, 4096, 1024);
    finalize_reduce<<<MTOK, 256, 0, stream>>>(z, part0, part1, b2,
                                              enc_out, mem, mcb, mcf, c);
    if (c > 0) {
      gemm_gate64<<<dim3(1024/64, 1024/64), 256, 0, stream>>>(
          mcb, wgate_h, b_gate, mcf, mem);
    }
  }
}